// Round 3
// baseline (452.828 us; speedup 1.0000x reference)
//
#include <hip/hip_runtime.h>

#define N_NODES_C 100000
#define N_EDGES_C 1600000
#define IN_F 64
#define OUT_F 64
#define NK 4
#define SCAN_BLK 256
#define NBLK ((N_NODES_C + SCAN_BLK - 1) / SCAN_BLK)   // 391

// ---------------------------------------------------------------------------
// proj: h[n][o][k] in bf16 (RNE). thread t: o = t>>2, k = t&3.
// ---------------------------------------------------------------------------
__global__ __launch_bounds__(256) void proj_kernel(
    const float* __restrict__ feat, const float* __restrict__ W,
    unsigned short* __restrict__ hb, int n_nodes)
{
    __shared__ float frow[IN_F];
    const int t = threadIdx.x;
    const int o = t >> 2;
    const int k = t & 3;
    float wreg[IN_F];
    {
        const float4* W4 = reinterpret_cast<const float4*>(W + (size_t)(k * OUT_F + o) * IN_F);
        #pragma unroll
        for (int i = 0; i < IN_F / 4; ++i) {
            float4 v = W4[i];
            wreg[4*i+0] = v.x; wreg[4*i+1] = v.y; wreg[4*i+2] = v.z; wreg[4*i+3] = v.w;
        }
    }
    for (int n = blockIdx.x; n < n_nodes; n += gridDim.x) {
        if (t < IN_F / 4) {
            float4 v = reinterpret_cast<const float4*>(feat + (size_t)n * IN_F)[t];
            frow[4*t+0] = v.x; frow[4*t+1] = v.y; frow[4*t+2] = v.z; frow[4*t+3] = v.w;
        }
        __syncthreads();
        float acc = 0.f;
        #pragma unroll
        for (int i = 0; i < IN_F; ++i) acc = fmaf(frow[i], wreg[i], acc);
        unsigned int u = __float_as_uint(acc);
        unsigned int r = (u + 0x7fffu + ((u >> 16) & 1u)) >> 16;
        hb[(size_t)n * 256 + t] = (unsigned short)r;
        __syncthreads();
    }
}

// ---------------------------------------------------------------------------
// counting sort by dst: hist -> 2-level scan -> scatter (g computed in scatter)
// ---------------------------------------------------------------------------
__global__ __launch_bounds__(256) void hist_zero(int* __restrict__ cnt) {
    int i = blockIdx.x * 256 + threadIdx.x;
    if (i < N_NODES_C) cnt[i] = 0;
}

__global__ __launch_bounds__(256) void hist_kernel(
    const int* __restrict__ dst, int* __restrict__ cnt, int n_edges)
{
    int e = blockIdx.x * 256 + threadIdx.x;
    if (e < n_edges) atomicAdd(&cnt[dst[e]], 1);
}

__global__ __launch_bounds__(256) void scan1_kernel(
    const int* __restrict__ cnt, int* __restrict__ bsum)
{
    __shared__ int s[SCAN_BLK];
    int i = blockIdx.x * SCAN_BLK + threadIdx.x;
    int v = (i < N_NODES_C) ? cnt[i] : 0;
    s[threadIdx.x] = v; __syncthreads();
    for (int off = SCAN_BLK / 2; off > 0; off >>= 1) {
        if (threadIdx.x < off) s[threadIdx.x] += s[threadIdx.x + off];
        __syncthreads();
    }
    if (threadIdx.x == 0) bsum[blockIdx.x] = s[0];
}

__global__ __launch_bounds__(512) void scan2_kernel(
    const int* __restrict__ bsum, int* __restrict__ boff)
{
    __shared__ int s[512];
    int t = threadIdx.x;
    int v = (t < NBLK) ? bsum[t] : 0;
    s[t] = v; __syncthreads();
    for (int off = 1; off < 512; off <<= 1) {
        int x = (t >= off) ? s[t - off] : 0;
        __syncthreads();
        s[t] += x;
        __syncthreads();
    }
    if (t < NBLK) boff[t] = s[t] - v;   // exclusive
}

__global__ __launch_bounds__(256) void scan3_kernel(
    const int* __restrict__ cnt, const int* __restrict__ boff,
    int* __restrict__ row_start, int* __restrict__ cursor)
{
    __shared__ int s[SCAN_BLK];
    int i = blockIdx.x * SCAN_BLK + threadIdx.x;
    int v = (i < N_NODES_C) ? cnt[i] : 0;
    s[threadIdx.x] = v; __syncthreads();
    for (int off = 1; off < SCAN_BLK; off <<= 1) {
        int x = (threadIdx.x >= off) ? s[threadIdx.x - off] : 0;
        __syncthreads();
        s[threadIdx.x] += x;
        __syncthreads();
    }
    if (i < N_NODES_C) {
        int ex = s[threadIdx.x] - v + boff[blockIdx.x];
        row_start[i] = ex;
        cursor[i] = ex;
    }
}

__global__ __launch_bounds__(256) void scatter_kernel(
    const int* __restrict__ src, const int* __restrict__ dst,
    const float* __restrict__ pseudo, const float* __restrict__ mu,
    const float* __restrict__ inv_sigma, int* __restrict__ cursor,
    int* __restrict__ ssrc, float4* __restrict__ sg, int n_edges)
{
    int e = blockIdx.x * 256 + threadIdx.x;
    if (e >= n_edges) return;
    const int d = dst[e];
    const int pos = atomicAdd(&cursor[d], 1);
    ssrc[pos] = src[e];
    const float p0 = pseudo[(size_t)e * 3 + 0];
    const float p1 = pseudo[(size_t)e * 3 + 1];
    const float p2 = pseudo[(size_t)e * 3 + 2];
    float4 g;
    float* gp = &g.x;
    #pragma unroll
    for (int k = 0; k < NK; ++k) {
        const float d0 = p0 - mu[k*3+0], d1 = p1 - mu[k*3+1], d2 = p2 - mu[k*3+2];
        const float s0 = inv_sigma[k*3+0], s1 = inv_sigma[k*3+1], s2 = inv_sigma[k*3+2];
        const float ex = -0.5f * (d0*d0*s0*s0 + d1*d1*s1*s1 + d2*d2*s2*s2);
        gp[k] = __expf(ex);
    }
    sg[pos] = g;
}

// ---------------------------------------------------------------------------
// gather: one wave per dst node, lane = output feature. No atomics.
// out[v] = sum_j g_j . h[src_j] + feat[v] + bias
// ---------------------------------------------------------------------------
__global__ __launch_bounds__(256) void gather_kernel(
    const int* __restrict__ row_start, const int* __restrict__ ssrc,
    const float4* __restrict__ sg, const unsigned short* __restrict__ hb,
    const float* __restrict__ feat, const float* __restrict__ bias,
    float* __restrict__ out, int n_nodes, int n_edges)
{
    const int lane = threadIdx.x & 63;
    const int v = (blockIdx.x * 256 + threadIdx.x) >> 6;
    if (v >= n_nodes) return;
    const int r0 = row_start[v];
    const int r1 = (v + 1 < n_nodes) ? row_start[v + 1] : n_edges;
    float acc = 0.f;
    for (int j = r0; j < r1; ++j) {
        const int s = ssrc[j];
        const float4 g = sg[j];
        const uint2 hv = *reinterpret_cast<const uint2*>(hb + (size_t)s * 256 + lane * 4);
        const float h0 = __uint_as_float(hv.x << 16);
        const float h1 = __uint_as_float(hv.x & 0xffff0000u);
        const float h2 = __uint_as_float(hv.y << 16);
        const float h3 = __uint_as_float(hv.y & 0xffff0000u);
        acc += g.x*h0 + g.y*h1 + g.z*h2 + g.w*h3;
    }
    out[(size_t)v * OUT_F + lane] = acc + feat[(size_t)v * OUT_F + lane] + bias[lane];
}

extern "C" void kernel_launch(void* const* d_in, const int* in_sizes, int n_in,
                              void* d_out, int out_size, void* d_ws, size_t ws_size,
                              hipStream_t stream) {
    const float* feat      = (const float*)d_in[0];
    const float* pseudo    = (const float*)d_in[1];
    const int*   src       = (const int*)d_in[2];
    const int*   dst       = (const int*)d_in[3];
    const float* W_fc      = (const float*)d_in[4];
    const float* mu        = (const float*)d_in[5];
    const float* inv_sigma = (const float*)d_in[6];
    const float* bias      = (const float*)d_in[7];
    float* out = (float*)d_out;

    char* ws = (char*)d_ws;
    unsigned short* hb = (unsigned short*)ws;            ws += (size_t)N_NODES_C * 256 * 2; // 51.2 MB
    float4* sg         = (float4*)ws;                    ws += (size_t)N_EDGES_C * 16;      // 25.6 MB
    int* ssrc          = (int*)ws;                       ws += (size_t)N_EDGES_C * 4;       // 6.4 MB
    int* cnt           = (int*)ws;                       ws += (size_t)N_NODES_C * 4;
    int* row_start     = (int*)ws;                       ws += (size_t)N_NODES_C * 4;
    int* cursor        = (int*)ws;                       ws += (size_t)N_NODES_C * 4;
    int* bsum          = (int*)ws;                       ws += 512 * 4;
    int* boff          = (int*)ws;                       ws += 512 * 4;

    const int eblk = (N_EDGES_C + 255) / 256;

    hist_zero<<<(N_NODES_C + 255) / 256, 256, 0, stream>>>(cnt);
    hist_kernel<<<eblk, 256, 0, stream>>>(dst, cnt, N_EDGES_C);
    scan1_kernel<<<NBLK, SCAN_BLK, 0, stream>>>(cnt, bsum);
    scan2_kernel<<<1, 512, 0, stream>>>(bsum, boff);
    scan3_kernel<<<NBLK, SCAN_BLK, 0, stream>>>(cnt, boff, row_start, cursor);
    scatter_kernel<<<eblk, 256, 0, stream>>>(src, dst, pseudo, mu, inv_sigma,
                                             cursor, ssrc, sg, N_EDGES_C);
    proj_kernel<<<2048, 256, 0, stream>>>(feat, W_fc, hb, N_NODES_C);
    gather_kernel<<<(N_NODES_C * 64 + 255) / 256, 256, 0, stream>>>(
        row_start, ssrc, sg, hb, feat, bias, out, N_NODES_C, N_EDGES_C);
}

// Round 4
// 378.274 us; speedup vs baseline: 1.1971x; 1.1971x over previous
//
#include <hip/hip_runtime.h>

#define N_NODES_C 100000
#define N_EDGES_C 1600000
#define IN_F 64
#define OUT_F 64
#define NK 4
#define SCAN_BLK 256
#define NBLK ((N_NODES_C + SCAN_BLK - 1) / SCAN_BLK)   // 391
#define SCAT_BLOCKS (N_EDGES_C / 256)                  // 6250 exact
#define PROJ_BLOCKS 1024

__device__ __forceinline__ unsigned int f2bf(float x) {
    unsigned int u = __float_as_uint(x);
    return (u + 0x7fffu + ((u >> 16) & 1u)) >> 16;
}
__device__ __forceinline__ float bflo(unsigned int u) { return __uint_as_float(u << 16); }
__device__ __forceinline__ float bfhi(unsigned int u) { return __uint_as_float(u & 0xffff0000u); }

// ---------------------------------------------------------------------------
// hist: count edges per dst (cnt pre-zeroed by memset)
// ---------------------------------------------------------------------------
__global__ __launch_bounds__(256) void hist_kernel(
    const int* __restrict__ dst, int* __restrict__ cnt, int n_edges)
{
    int e = blockIdx.x * 256 + threadIdx.x;
    if (e < n_edges) atomicAdd(&cnt[dst[e]], 1);
}

// ---------------------------------------------------------------------------
// scan1: per-block sums of cnt
// ---------------------------------------------------------------------------
__global__ __launch_bounds__(256) void scan1_kernel(
    const int* __restrict__ cnt, int* __restrict__ bsum)
{
    __shared__ int s[SCAN_BLK];
    int i = blockIdx.x * SCAN_BLK + threadIdx.x;
    int v = (i < N_NODES_C) ? cnt[i] : 0;
    s[threadIdx.x] = v; __syncthreads();
    for (int off = SCAN_BLK / 2; off > 0; off >>= 1) {
        if (threadIdx.x < off) s[threadIdx.x] += s[threadIdx.x + off];
        __syncthreads();
    }
    if (threadIdx.x == 0) bsum[blockIdx.x] = s[0];
}

// ---------------------------------------------------------------------------
// scan23: each block computes its own bsum-prefix, then local exclusive scan.
// Writes row_start[0..N] (sentinel at N) and cursor.
// ---------------------------------------------------------------------------
__global__ __launch_bounds__(256) void scan23_kernel(
    const int* __restrict__ cnt, const int* __restrict__ bsum,
    int* __restrict__ row_start, int* __restrict__ cursor)
{
    __shared__ int pre[SCAN_BLK];
    __shared__ int s[SCAN_BLK];
    const int t = threadIdx.x;
    int p = 0;
    for (int i = t; i < (int)blockIdx.x; i += SCAN_BLK) p += bsum[i];
    pre[t] = p; __syncthreads();
    for (int off = SCAN_BLK / 2; off > 0; off >>= 1) {
        if (t < off) pre[t] += pre[t + off];
        __syncthreads();
    }
    const int boff = pre[0];
    const int i = blockIdx.x * SCAN_BLK + t;
    int v = (i < N_NODES_C) ? cnt[i] : 0;
    s[t] = v; __syncthreads();
    for (int off = 1; off < SCAN_BLK; off <<= 1) {
        int x = (t >= off) ? s[t - off] : 0;
        __syncthreads();
        s[t] += x;
        __syncthreads();
    }
    if (i < N_NODES_C) {
        int ex = s[t] - v + boff;
        row_start[i] = ex;
        cursor[i] = ex;
        if (i == N_NODES_C - 1) row_start[N_NODES_C] = ex + v;
    }
}

// ---------------------------------------------------------------------------
// fused scatter (blocks [0, SCAT_BLOCKS)) + proj (remaining blocks)
// scatter: one 16B record per edge {src, pack(g0,g1), pack(g2,g3), 0}
// proj:    h[n][o][k] bf16, 4 nodes per barrier, float4 LDS reads
// ---------------------------------------------------------------------------
__global__ __launch_bounds__(256) void scatter_proj_kernel(
    const int* __restrict__ src, const int* __restrict__ dst,
    const float* __restrict__ pseudo, const float* __restrict__ mu,
    const float* __restrict__ inv_sigma, int* __restrict__ cursor,
    uint4* __restrict__ rec,
    const float* __restrict__ feat, const float* __restrict__ W,
    unsigned short* __restrict__ hbuf, int n_edges, int n_nodes)
{
    if (blockIdx.x < SCAT_BLOCKS) {
        const int e = blockIdx.x * 256 + threadIdx.x;
        if (e >= n_edges) return;
        const int d = dst[e];
        const float p0 = pseudo[(size_t)e * 3 + 0];
        const float p1 = pseudo[(size_t)e * 3 + 1];
        const float p2 = pseudo[(size_t)e * 3 + 2];
        float g[NK];
        #pragma unroll
        for (int k = 0; k < NK; ++k) {
            const float d0 = p0 - mu[k*3+0], d1 = p1 - mu[k*3+1], d2 = p2 - mu[k*3+2];
            const float s0 = inv_sigma[k*3+0], s1 = inv_sigma[k*3+1], s2 = inv_sigma[k*3+2];
            const float ex = -0.5f * (d0*d0*s0*s0 + d1*d1*s1*s1 + d2*d2*s2*s2);
            g[k] = __expf(ex);
        }
        const int pos = atomicAdd(&cursor[d], 1);
        uint4 r;
        r.x = (unsigned int)src[e];
        r.y = f2bf(g[0]) | (f2bf(g[1]) << 16);
        r.z = f2bf(g[2]) | (f2bf(g[3]) << 16);
        r.w = 0u;
        rec[pos] = r;
    } else {
        __shared__ float frow[4][IN_F];
        const int t = threadIdx.x;
        const int o = t >> 2;
        const int k = t & 3;
        float wreg[IN_F];
        {
            const float4* W4 = reinterpret_cast<const float4*>(W + (size_t)(k * OUT_F + o) * IN_F);
            #pragma unroll
            for (int i = 0; i < IN_F / 4; ++i) {
                float4 v = W4[i];
                wreg[4*i+0] = v.x; wreg[4*i+1] = v.y; wreg[4*i+2] = v.z; wreg[4*i+3] = v.w;
            }
        }
        const int nq = n_nodes >> 2;                 // 25000 (n_nodes % 4 == 0)
        const int nb = gridDim.x - SCAT_BLOCKS;
        const int r = t >> 6, c = t & 63;
        for (int q = blockIdx.x - SCAT_BLOCKS; q < nq; q += nb) {
            const int n0 = q << 2;
            frow[r][c] = feat[(size_t)(n0 + r) * IN_F + c];
            __syncthreads();
            float a0 = 0.f, a1 = 0.f, a2 = 0.f, a3 = 0.f;
            #pragma unroll
            for (int i0 = 0; i0 < IN_F; i0 += 4) {
                const float4 f0 = *(const float4*)&frow[0][i0];
                const float4 f1 = *(const float4*)&frow[1][i0];
                const float4 f2 = *(const float4*)&frow[2][i0];
                const float4 f3 = *(const float4*)&frow[3][i0];
                const float w0 = wreg[i0], w1 = wreg[i0+1], w2 = wreg[i0+2], w3 = wreg[i0+3];
                a0 = fmaf(f0.x,w0, fmaf(f0.y,w1, fmaf(f0.z,w2, fmaf(f0.w,w3, a0))));
                a1 = fmaf(f1.x,w0, fmaf(f1.y,w1, fmaf(f1.z,w2, fmaf(f1.w,w3, a1))));
                a2 = fmaf(f2.x,w0, fmaf(f2.y,w1, fmaf(f2.z,w2, fmaf(f2.w,w3, a2))));
                a3 = fmaf(f3.x,w0, fmaf(f3.y,w1, fmaf(f3.z,w2, fmaf(f3.w,w3, a3))));
            }
            hbuf[(size_t)(n0+0)*256 + t] = (unsigned short)f2bf(a0);
            hbuf[(size_t)(n0+1)*256 + t] = (unsigned short)f2bf(a1);
            hbuf[(size_t)(n0+2)*256 + t] = (unsigned short)f2bf(a2);
            hbuf[(size_t)(n0+3)*256 + t] = (unsigned short)f2bf(a3);
            __syncthreads();
        }
    }
}

// ---------------------------------------------------------------------------
// gather: one wave per dst node, lane = output feature, unroll x4 for MLP.
// ---------------------------------------------------------------------------
__global__ __launch_bounds__(256) void gather_kernel(
    const int* __restrict__ row_start, const uint4* __restrict__ rec,
    const unsigned short* __restrict__ hb,
    const float* __restrict__ feat, const float* __restrict__ bias,
    float* __restrict__ out, int n_nodes)
{
    const int lane = threadIdx.x & 63;
    const int v = (blockIdx.x * 256 + threadIdx.x) >> 6;
    if (v >= n_nodes) return;
    const int r0 = row_start[v];
    const int r1 = row_start[v + 1];
    float acc = 0.f;
    int j = r0;
    for (; j + 4 <= r1; j += 4) {
        const uint4 ra = rec[j+0];
        const uint4 rb = rec[j+1];
        const uint4 rc = rec[j+2];
        const uint4 rd = rec[j+3];
        const uint2 ha = *(const uint2*)(hb + (size_t)ra.x * 256 + lane * 4);
        const uint2 hbv= *(const uint2*)(hb + (size_t)rb.x * 256 + lane * 4);
        const uint2 hc = *(const uint2*)(hb + (size_t)rc.x * 256 + lane * 4);
        const uint2 hd = *(const uint2*)(hb + (size_t)rd.x * 256 + lane * 4);
        acc += bflo(ra.y)*bflo(ha.x) + bfhi(ra.y)*bfhi(ha.x)
             + bflo(ra.z)*bflo(ha.y) + bfhi(ra.z)*bfhi(ha.y);
        acc += bflo(rb.y)*bflo(hbv.x) + bfhi(rb.y)*bfhi(hbv.x)
             + bflo(rb.z)*bflo(hbv.y) + bfhi(rb.z)*bfhi(hbv.y);
        acc += bflo(rc.y)*bflo(hc.x) + bfhi(rc.y)*bfhi(hc.x)
             + bflo(rc.z)*bflo(hc.y) + bfhi(rc.z)*bfhi(hc.y);
        acc += bflo(rd.y)*bflo(hd.x) + bfhi(rd.y)*bfhi(hd.x)
             + bflo(rd.z)*bflo(hd.y) + bfhi(rd.z)*bfhi(hd.y);
    }
    for (; j < r1; ++j) {
        const uint4 ra = rec[j];
        const uint2 ha = *(const uint2*)(hb + (size_t)ra.x * 256 + lane * 4);
        acc += bflo(ra.y)*bflo(ha.x) + bfhi(ra.y)*bfhi(ha.x)
             + bflo(ra.z)*bflo(ha.y) + bfhi(ra.z)*bfhi(ha.y);
    }
    out[(size_t)v * OUT_F + lane] = acc + feat[(size_t)v * OUT_F + lane] + bias[lane];
}

extern "C" void kernel_launch(void* const* d_in, const int* in_sizes, int n_in,
                              void* d_out, int out_size, void* d_ws, size_t ws_size,
                              hipStream_t stream) {
    const float* feat      = (const float*)d_in[0];
    const float* pseudo    = (const float*)d_in[1];
    const int*   src       = (const int*)d_in[2];
    const int*   dst       = (const int*)d_in[3];
    const float* W_fc      = (const float*)d_in[4];
    const float* mu        = (const float*)d_in[5];
    const float* inv_sigma = (const float*)d_in[6];
    const float* bias      = (const float*)d_in[7];
    float* out = (float*)d_out;

    char* ws = (char*)d_ws;
    unsigned short* hb = (unsigned short*)ws;  ws += (size_t)N_NODES_C * 256 * 2;   // 51.2 MB
    uint4* rec         = (uint4*)ws;           ws += (size_t)N_EDGES_C * 16;        // 25.6 MB
    int* cnt           = (int*)ws;             ws += (size_t)N_NODES_C * 4;
    int* row_start     = (int*)ws;             ws += (size_t)(N_NODES_C + 4) * 4;
    int* cursor        = (int*)ws;             ws += (size_t)N_NODES_C * 4;
    int* bsum          = (int*)ws;             ws += 512 * 4;

    hipMemsetAsync(cnt, 0, (size_t)N_NODES_C * 4, stream);
    hist_kernel<<<SCAT_BLOCKS, 256, 0, stream>>>(dst, cnt, N_EDGES_C);
    scan1_kernel<<<NBLK, SCAN_BLK, 0, stream>>>(cnt, bsum);
    scan23_kernel<<<NBLK, SCAN_BLK, 0, stream>>>(cnt, bsum, row_start, cursor);
    scatter_proj_kernel<<<SCAT_BLOCKS + PROJ_BLOCKS, 256, 0, stream>>>(
        src, dst, pseudo, mu, inv_sigma, cursor, rec, feat, W_fc, hb,
        N_EDGES_C, N_NODES_C);
    gather_kernel<<<(N_NODES_C * 64 + 255) / 256, 256, 0, stream>>>(
        row_start, rec, hb, feat, bias, out, N_NODES_C);
}